// Round 6
// baseline (573.263 us; speedup 1.0000x reference)
//
#include <hip/hip_runtime.h>

// (B,T,C,H) = (8,2048,1024,16), D=64
#define Tdim 2048

typedef __attribute__((ext_vector_type(8))) short bf16x8;
typedef __attribute__((ext_vector_type(4))) float f32x4;
typedef __attribute__((ext_vector_type(4))) short short4v;

#define GLOBAL_U32(p) ((const __attribute__((address_space(1))) unsigned int*)(p))
#define LDS_U32(p)    ((__attribute__((address_space(3))) unsigned int*)(p))

// barrier with compiler memory fences (no instruction-order pinning)
#define BARRIER() do { asm volatile("" ::: "memory"); \
                       __builtin_amdgcn_s_barrier(); \
                       asm volatile("" ::: "memory"); } while (0)

__device__ __forceinline__ float phi_f(float x) {
    return x > 0.f ? (x + 1.f) : __expf(x);
}
// round-to-nearest-even fp32 -> bf16 (finite inputs only)
__device__ __forceinline__ short f2bf(float f) {
    unsigned u = __float_as_uint(f);
    u += 0x7fffu + ((u >> 16) & 1u);
    return (short)(u >> 16);
}
__device__ __forceinline__ float bf2f(short h) {
    return __uint_as_float(((unsigned)(unsigned short)h) << 16);
}

// ===========================================================================
// TILED layout: matrix [R x K] bf16 stored as tiles of 16 rows x 32 k.
// Tile (rt, kt) at ((rt*(K/32))+kt)*512 shorts; slot L (0..63) holds
// row rt*16+(L&15), k = kt*32+(L>>4)*8 .. +8.  One wave staging instr = 1 KB
// contiguous; fragment read = tile_base + lane*16B (conflict-free identity).
//
// Y-SCRATCH layout (GEMM2's A): same tile format, but tiles embedded in the
// dead k-region of qkv.  Tile (RT, kt, plane) at physical row RT*16 + hh
// (hh = kt>>1), shorts offset 2048 + ((kt&1)*2 + plane)*512.  Each tile is
// 1 KB contiguous => staging identical to TILED (wave-uniform + lane*16B).
//
// KVT layout (attn_y's B): per bh, kv^T[f=64][d=64] as TILED bf16:
// 8 hi tiles (tt = nt*2 + kt) at [0..4096) shorts, 8 lo tiles at [4096..8192).
// ===========================================================================

// ---------------------------------------------------------------------------
// x [16384 x 1024] fp32 -> tiled split hi/lo. Block: 16 rows x 128 cols.
// ---------------------------------------------------------------------------
__global__ __launch_bounds__(256) void split_tile_kernel(
    const float* __restrict__ X, short* __restrict__ Hi, short* __restrict__ Lo)
{
    const int rt = blockIdx.x;          // row-tile 0..1023
    const int cb = blockIdx.y;          // col-block 0..7 (128 cols)
    const int t = threadIdx.x;
    const int rl = t >> 4;              // row in tile 0..15
    const int cc = t & 15;              // col-chunk (8 cols) 0..15

    const float* xp = X + ((size_t)rt * 16 + rl) * 1024 + cb * 128 + cc * 8;
    const float4 a = *(const float4*)xp;
    const float4 b = *(const float4*)(xp + 4);
    float v[8] = {a.x, a.y, a.z, a.w, b.x, b.y, b.z, b.w};
    bf16x8 h, l;
#pragma unroll
    for (int j = 0; j < 8; ++j) {
        const short hh = f2bf(v[j]);
        h[j] = hh;
        l[j] = f2bf(v[j] - bf2f(hh));
    }
    const int kt = cb * 4 + (cc >> 2);
    const int slot = ((cc & 3) << 4) | rl;
    const size_t off = ((size_t)rt * 32 + kt) * 512 + slot * 8;
    *(bf16x8*)(Hi + off) = h;
    *(bf16x8*)(Lo + off) = l;
}

// ---------------------------------------------------------------------------
// W [1024 x N] fp32 -> W^T [N x 1024] tiled split hi/lo. One wave per tile.
// nkt = 1024/32 = 32 (hardcoded).
// ---------------------------------------------------------------------------
__global__ __launch_bounds__(256) void w_tile_kernel(
    const float* __restrict__ W, int N,
    short* __restrict__ Thi, short* __restrict__ Tlo)
{
    const int tile = blockIdx.x * 4 + (threadIdx.x >> 6);
    const int nt = tile >> 5;           // n-tile
    const int kt = tile & 31;           // k-tile
    const int lane = threadIdx.x & 63;
    const int n = nt * 16 + (lane & 15);
    const int k = kt * 32 + (lane >> 4) * 8;
    const float* wp = W + (size_t)k * N + n;
    bf16x8 h, l;
#pragma unroll
    for (int j = 0; j < 8; ++j) {
        const float v = wp[(size_t)j * N];
        const short hh = f2bf(v);
        h[j] = hh;
        l[j] = f2bf(v - bf2f(hh));
    }
    const size_t off = (size_t)tile * 512 + lane * 8;
    *(bf16x8*)(Thi + off) = h;
    *(bf16x8*)(Tlo + off) = l;
}

// ---------------------------------------------------------------------------
// bf16x3 split-precision GEMM: C = (Ahi+Alo)[M,K] * (Bhi+Blo)^T[N,K] + bias
// (drops lo*lo).
//
// 256x256 block tile, BK=32, 8 waves (2m x 4n), per-wave output 128x64.
// Double-buffered LDS (2 x 64 KiB).  COUNTED-VMCNT role-split schedule
// (round-5 proven: 247 us, MfmaUtil ~58%): waves 0-3 stage A-planes,
// waves 4-7 stage B-planes.  Per K-step:
//   P0: B-waves issue next-step loads | all read B(cur) frags |
//       A-waves s_waitcnt vmcnt(0) (loads one compute cluster old -> free)
//       | barrier
//   P1: A-waves issue next-step loads | A-reads + 96 MFMA (setprio) |
//       B-waves vmcnt(0) (covered by the MFMA cluster -> free) | barrier
//
// B always TILED.  AMODE 0: A TILED.  AMODE 2: A = y-scratch tiles embedded
// in qkv (see header comment).  Fragment read = identity lane*8.  K = 1024.
// ---------------------------------------------------------------------------
template<int AMODE>
__global__ __launch_bounds__(512, 2) void gemm3_kernel(
    const short* __restrict__ Ahi, const short* __restrict__ Alo, int lda,
    const short* __restrict__ BThi, const short* __restrict__ BTlo,
    const float* __restrict__ bias, float* __restrict__ C,
    int K, int ldc)
{
    // [2 buf][4 arrays][16 tiles][512 shorts] = 128 KiB
    __shared__ short smem[65536];
    const int tid = threadIdx.x;
    const int lane = tid & 63;
    const int wid = tid >> 6;            // wave 0..7
    const int bx = blockIdx.x, by = blockIdx.y;
    const int wm = wid >> 2, wn = wid & 3;

    const size_t tilestep = (size_t)(K >> 5) * 512;   // shorts per row-tile

    // staging: wave w stages 8 tiles of array sel (0:Ahi 1:Alo 2:Bhi 3:Blo),
    // half h (tiles h*8 .. h*8+7).  A-waves = wid 0..3, B-waves = wid 4..7.
    const int sel = wid >> 1, half = wid & 1;
    const bool is_a_wave = (wid < 4);
    const short* gptr;
    if (sel >= 2) {
        const short* gb = (sel == 2) ? BThi : BTlo;
        gptr = gb + (size_t)(bx * 16 + half * 8) * tilestep + lane * 8;
    } else if (AMODE == 0) {
        const short* gb = (sel == 0) ? Ahi : Alo;
        gptr = gb + (size_t)(by * 16 + half * 8) * tilestep + lane * 8;
    } else {
        // AMODE 2: y-scratch tiles in qkv; row-tile RT starts at physical
        // row RT*16; plane offset handled in the k-offset below.
        gptr = Ahi + (size_t)((by * 16 + half * 8) * 16) * 6144 + 2048 + lane * 8;
    }
    // wave-uniform LDS dest base (buffer 0)
    short* lw = smem + sel * 8192 + half * 4096;

    f32x4 acc[8][4];
#pragma unroll
    for (int i = 0; i < 8; ++i)
#pragma unroll
        for (int j = 0; j < 4; ++j) acc[i][j] = (f32x4){0.f, 0.f, 0.f, 0.f};

    auto stage = [&](int buf, int k0) {
        short* lb = lw + buf * 32768;
        if (AMODE == 0 || sel >= 2) {
            const short* g = gptr + (size_t)(k0 >> 5) * 512;
#pragma unroll
            for (int c = 0; c < 8; ++c)
                __builtin_amdgcn_global_load_lds(
                    GLOBAL_U32(g + (size_t)c * tilestep),
                    LDS_U32(lb + c * 512), 16, 0, 0);
        } else {
            // tile (RT, kt=k0>>5, plane=sel): row r = kt>>1 (= head), slot
            // s = (kt&1)*2 + plane; addr = (RT*16 + r)*6144 + 2048 + s*512
            const size_t koff = (size_t)(k0 >> 6) * 6144
                              + (size_t)((((k0 >> 5) & 1) << 1) | sel) * 512;
            const short* g = gptr + koff;
#pragma unroll
            for (int c = 0; c < 8; ++c)
                __builtin_amdgcn_global_load_lds(
                    GLOBAL_U32(g + (size_t)(c * 16) * 6144),
                    LDS_U32(lb + c * 512), 16, 0, 0);
        }
    };

    // prologue: fill buffer 0 completely (full drain + barrier, once)
    stage(0, 0);
    __syncthreads();

    const int fo = lane * 8;
    int cur = 0;
    for (int k0 = 0; k0 < K; k0 += 32) {
        const short* bp = smem + cur * 32768;
        // clamped next-step index: last iter re-stages k0=0 into the
        // never-read buffer (keeps per-wave vmcnt counts uniform)
        const int k0n = (k0 + 32 < K) ? (k0 + 32) : 0;

        // ---- P0: B-wave issue | B-reads | A-wave publish | barrier ----
        if (!is_a_wave) stage(cur ^ 1, k0n);
        bf16x8 bh[4], bl[4];
#pragma unroll
        for (int j = 0; j < 4; ++j) {
            bh[j] = *(const bf16x8*)(bp + 16384 + (wn * 4 + j) * 512 + fo);
            bl[j] = *(const bf16x8*)(bp + 24576 + (wn * 4 + j) * 512 + fo);
        }
        if (is_a_wave) asm volatile("s_waitcnt vmcnt(0)" ::: "memory");
        BARRIER();   // A(cur) now published by all A-waves

        // ---- P1: A-wave issue | A-reads + MFMA | B-wave publish | barrier --
        if (is_a_wave) stage(cur ^ 1, k0n);
        __builtin_amdgcn_s_setprio(1);
#pragma unroll
        for (int i = 0; i < 8; ++i) {
            const bf16x8 ah = *(const bf16x8*)(bp + (wm * 8 + i) * 512 + fo);
            const bf16x8 al = *(const bf16x8*)(bp + 8192 + (wm * 8 + i) * 512 + fo);
#pragma unroll
            for (int j = 0; j < 4; ++j) {
                acc[i][j] = __builtin_amdgcn_mfma_f32_16x16x32_bf16(ah, bh[j], acc[i][j], 0, 0, 0);
                acc[i][j] = __builtin_amdgcn_mfma_f32_16x16x32_bf16(al, bh[j], acc[i][j], 0, 0, 0);
                acc[i][j] = __builtin_amdgcn_mfma_f32_16x16x32_bf16(ah, bl[j], acc[i][j], 0, 0, 0);
            }
        }
        __builtin_amdgcn_s_setprio(0);
        if (!is_a_wave) asm volatile("s_waitcnt vmcnt(0)" ::: "memory");
        BARRIER();   // B(next) published; buf cur fully consumed
        cur ^= 1;
    }

    // epilogue: C/D layout col=lane&15, row=(lane>>4)*4+reg
    const int fr = lane & 15, fq = lane >> 4;
#pragma unroll
    for (int i = 0; i < 8; ++i) {
        const size_t row0 = (size_t)by * 256 + wm * 128 + i * 16 + fq * 4;
#pragma unroll
        for (int j = 0; j < 4; ++j) {
            const int col = bx * 256 + wn * 64 + j * 16 + fr;
            const float bv = bias[col];
            float* cp = C + row0 * (size_t)ldc + col;
#pragma unroll
            for (int r = 0; r < 4; ++r)
                cp[(size_t)r * ldc] = acc[i][j][r] + bv;
        }
    }
}

// ---------------------------------------------------------------------------
// Partial kv/ksum per (T-chunk, bh): 8 x 128 = 1024 blocks.
// ---------------------------------------------------------------------------
__global__ __launch_bounds__(256) void kv_part_kernel(
    const float* __restrict__ qkv, const int* __restrict__ attn,
    float* __restrict__ kvpart, float* __restrict__ kspart)
{
    __shared__ float ks[32][64];
    __shared__ float vs[32][64];

    const int chunk = blockIdx.x;       // 0..7
    const int bh = blockIdx.y;          // 0..127
    const int b = bh >> 4;
    const int h = bh & 15;
    const int tid = threadIdx.x;
    const int tx = tid & 15;
    const int ty = tid >> 4;
    const int l_t = tid >> 4;
    const int l_d = (tid & 15) << 2;

    const float* kb = qkv + (size_t)b * Tdim * 3072 + 1024 + h * 64;
    const float* vb = qkv + (size_t)b * Tdim * 3072 + 2048 + h * 64;
    const int* am = attn + b * Tdim;

    float acc[4][4];
#pragma unroll
    for (int i = 0; i < 4; ++i)
#pragma unroll
        for (int j = 0; j < 4; ++j) acc[i][j] = 0.f;
    float ksl = 0.f;

    for (int t0 = chunk * 256; t0 < (chunk + 1) * 256; t0 += 32) {
        __syncthreads();
#pragma unroll
        for (int rr = 0; rr < 2; ++rr) {
            const int t = l_t + rr * 16;
            const int gt = t0 + t;
            const float m = (am[gt] > 0) ? 1.f : 0.f;
            const float4 k4 = *(const float4*)(kb + (size_t)gt * 3072 + l_d);
            const float4 v4 = *(const float4*)(vb + (size_t)gt * 3072 + l_d);
            float4 kp, vp;
            kp.x = phi_f(k4.x) * m; kp.y = phi_f(k4.y) * m;
            kp.z = phi_f(k4.z) * m; kp.w = phi_f(k4.w) * m;
            vp.x = v4.x * m; vp.y = v4.y * m; vp.z = v4.z * m; vp.w = v4.w * m;
            *(float4*)&ks[t][l_d] = kp;
            *(float4*)&vs[t][l_d] = vp;
        }
        __syncthreads();
#pragma unroll
        for (int t = 0; t < 32; ++t) {
            float kr[4], vr[4];
            *(float4*)kr = *(const float4*)&ks[t][ty * 4];
            *(float4*)vr = *(const float4*)&vs[t][tx * 4];
#pragma unroll
            for (int i = 0; i < 4; ++i)
#pragma unroll
                for (int j = 0; j < 4; ++j)
                    acc[i][j] = fmaf(kr[i], vr[j], acc[i][j]);
        }
        if (tid < 64) {
#pragma unroll
            for (int t = 0; t < 32; ++t) ksl += ks[t][tid];
        }
    }

    float* ko = kvpart + ((size_t)bh * 8 + chunk) * 4096;
#pragma unroll
    for (int i = 0; i < 4; ++i) {
        float4 o;
        o.x = acc[i][0]; o.y = acc[i][1]; o.z = acc[i][2]; o.w = acc[i][3];
        *(float4*)(ko + (ty * 4 + i) * 64 + tx * 4) = o;
    }
    if (tid < 64) kspart[((size_t)bh * 8 + chunk) * 64 + tid] = ksl;
}

// ---------------------------------------------------------------------------
// Reduce partials AND emit kv^T as TILED bf16 hi/lo fragments (KVT layout)
// + ksum fp32.  Thread tid holds kv[d0+{0,16,32,48}][f0..f0+3] after the
// reduce (d0=tid>>4, f0=(tid&15)*4); transpose via padded LDS.
// ---------------------------------------------------------------------------
__global__ __launch_bounds__(256) void kv_reduce_kernel(
    const float* __restrict__ kvpart, const float* __restrict__ kspart,
    short* __restrict__ kvT, float* __restrict__ ksum)
{
    __shared__ float kvs[64][68];   // 68: rows 16B-aligned, bank-spread
    const int bh = blockIdx.x;
    const int tid = threadIdx.x;
    const float4* p = (const float4*)(kvpart + (size_t)bh * 8 * 4096);
    float4 s0 = {0,0,0,0}, s1 = {0,0,0,0}, s2 = {0,0,0,0}, s3 = {0,0,0,0};
#pragma unroll
    for (int c = 0; c < 8; ++c) {
        const int base = c * 1024;
        float4 a = p[base + tid], b = p[base + 256 + tid],
               cc = p[base + 512 + tid], d = p[base + 768 + tid];
        s0.x += a.x; s0.y += a.y; s0.z += a.z; s0.w += a.w;
        s1.x += b.x; s1.y += b.y; s1.z += b.z; s1.w += b.w;
        s2.x += cc.x; s2.y += cc.y; s2.z += cc.z; s2.w += cc.w;
        s3.x += d.x; s3.y += d.y; s3.z += d.z; s3.w += d.w;
    }
    const int d0 = tid >> 4, f0 = (tid & 15) * 4;
    *(float4*)&kvs[d0 +  0][f0] = s0;
    *(float4*)&kvs[d0 + 16][f0] = s1;
    *(float4*)&kvs[d0 + 32][f0] = s2;
    *(float4*)&kvs[d0 + 48][f0] = s3;
    __syncthreads();

    // emit 8 hi tiles + 8 lo tiles of kv^T[f][d] (TILED: row=f, k=d)
    short* kvb = kvT + (size_t)bh * 8192;
#pragma unroll
    for (int pp = 0; pp < 2; ++pp) {
        const int sid = tid * 2 + pp;       // 0..511
        const int tt = sid >> 6;            // tile 0..7 (nt*2+kt)
        const int L = sid & 63;
        const int nt = tt >> 1, kt = tt & 1;
        const int f = nt * 16 + (L & 15);
        const int dd = kt * 32 + (L >> 4) * 8;
        bf16x8 h, l;
#pragma unroll
        for (int e = 0; e < 8; ++e) {
            const float v = kvs[dd + e][f];
            const short hh = f2bf(v);
            h[e] = hh;
            l[e] = f2bf(v - bf2f(hh));
        }
        *(bf16x8*)(kvb + tt * 512 + L * 8) = h;
        *(bf16x8*)(kvb + 4096 + tt * 512 + L * 8) = l;
    }
    if (tid < 64) {
        float ss = 0.f;
#pragma unroll
        for (int c = 0; c < 8; ++c) ss += kspart[((size_t)bh * 8 + c) * 64 + tid];
        ksum[bh * 64 + tid] = ss;
    }
}

// ---------------------------------------------------------------------------
// MFMA attn_y: y[t][f] = (phi(q[t])·kv[:,f]) / max(phi(q[t])·ksum, 1e-8).
// Block = (64 q-rows, bh); 4 waves x 16 rows.  kv^T staged via
// global_load_lds (16 KiB); q read global->reg, phi+split in reg (A-frags);
// denominator = per-lane dot with ksum + shfl_xor reduce; numerator =
// 24 MFMA/wave (bf16x3).  Writes y hi/lo in TILED format into the dead
// k-region of qkv (same Y-SCRATCH layout GEMM2 AMODE2 consumes).
// ---------------------------------------------------------------------------
__global__ __launch_bounds__(256) void attn_y_kernel(
    float* __restrict__ qkv, const short* __restrict__ kvT,
    const float* __restrict__ ksumin)
{
    __shared__ short kvs[8192];       // 16 KiB: 8 hi + 8 lo tiles
    __shared__ float den_s[4][16];

    const int bh = blockIdx.y;
    const int b = bh >> 4;
    const int hh = bh & 15;
    const int t0 = blockIdx.x * 64;
    const int tid = threadIdx.x;
    const int lane = tid & 63;
    const int wid = tid >> 6;

    // stage kv^T tiles: wave w -> tiles w*4 .. w*4+3 (1 KB each, identity)
    {
        const short* src = kvT + (size_t)bh * 8192 + (wid * 4) * 512 + lane * 8;
        short* dst = kvs + (wid * 4) * 512;
#pragma unroll
        for (int t = 0; t < 4; ++t)
            __builtin_amdgcn_global_load_lds(
                GLOBAL_U32(src + t * 512), LDS_U32(dst + t * 512), 16, 0, 0);
    }

    // load q (global->reg), phi, denominator partial, hi/lo split
    const int grow = b * Tdim + t0 + wid * 16 + (lane & 15);
    const int kc = (lane >> 4) * 8;
    const float* qp = qkv + (size_t)grow * 3072 + hh * 64 + kc;
    const float* kp = ksumin + bh * 64 + kc;
    bf16x8 ah[2], al[2];
    float den = 0.f;
#pragma unroll
    for (int ks = 0; ks < 2; ++ks) {
        const float4 a = *(const float4*)(qp + ks * 32);
        const float4 c = *(const float4*)(qp + ks * 32 + 4);
        const float4 u = *(const float4*)(kp + ks * 32);
        const float4 w = *(const float4*)(kp + ks * 32 + 4);
        float qv[8] = {a.x, a.y, a.z, a.w, c.x, c.y, c.z, c.w};
        float sv[8] = {u.x, u.y, u.z, u.w, w.x, w.y, w.z, w.w};
#pragma unroll
        for (int e = 0; e < 8; ++e) {
            const float ph = phi_f(qv[e]);
            den = fmaf(ph, sv[e], den);
            const short hi = f2bf(ph);
            ah[ks][e] = hi;
            al[ks][e] = f2bf(ph - bf2f(hi));
        }
    }
    den += __shfl_xor(den, 16);
    den += __shfl_xor(den, 32);
    if ((lane >> 4) == 0) den_s[wid][lane & 15] = den;
    __syncthreads();     // staging (vmcnt) drained + den_s visible

    // numerator: acc[j] = phi_q[16x64] . kvT-tile j  (bf16x3)
    f32x4 acc[4];
#pragma unroll
    for (int j = 0; j < 4; ++j) acc[j] = (f32x4){0.f, 0.f, 0.f, 0.f};
#pragma unroll
    for (int j = 0; j < 4; ++j) {
#pragma unroll
        for (int ks = 0; ks < 2; ++ks) {
            const short* tb = kvs + (j * 2 + ks) * 512 + lane * 8;
            const bf16x8 bhf = *(const bf16x8*)tb;
            const bf16x8 blf = *(const bf16x8*)(tb + 4096);
            acc[j] = __builtin_amdgcn_mfma_f32_16x16x32_bf16(ah[ks], bhf, acc[j], 0, 0, 0);
            acc[j] = __builtin_amdgcn_mfma_f32_16x16x32_bf16(al[ks], bhf, acc[j], 0, 0, 0);
            acc[j] = __builtin_amdgcn_mfma_f32_16x16x32_bf16(ah[ks], blf, acc[j], 0, 0, 0);
        }
    }

    // per-C-row 1/den  (C/D row = (lane>>4)*4 + r)
    float dinv[4];
#pragma unroll
    for (int r = 0; r < 4; ++r)
        dinv[r] = 1.f / fmaxf(den_s[wid][(lane >> 4) * 4 + r], 1e-8f);

    // tiled y-scratch write: rows t0+wid*16+rloc, cols c = j*16+(lane&15)
    short* yb = (short*)qkv;
    const int RT = ((b * Tdim + t0) >> 4) + wid;
    const size_t rowbase = (size_t)(RT * 16 + hh) * 6144 + 2048;
#pragma unroll
    for (int j = 0; j < 4; ++j) {
        const int c = j * 16 + (lane & 15);
        const int kl = c >> 5;              // k-tile within head (0/1)
        const int cc = (c & 31) >> 3;       // k-chunk within tile
        const int wi = c & 7;               // offset within 8-short chunk
        const size_t so = rowbase + (size_t)(kl * 2) * 512
                        + (size_t)(cc << 4) * 8 + wi;
#pragma unroll
        for (int r = 0; r < 4; ++r) {
            const int rloc = (lane >> 4) * 4 + r;
            const float val = acc[j][r] * dinv[r];
            const short h = f2bf(val);
            yb[so + (size_t)rloc * 8] = h;                     // hi plane
            yb[so + 512 + (size_t)rloc * 8] = f2bf(val - bf2f(h)); // lo plane
        }
    }
}

// ---------------------------------------------------------------------------
extern "C" void kernel_launch(void* const* d_in, const int* in_sizes, int n_in,
                              void* d_out, int out_size, void* d_ws, size_t ws_size,
                              hipStream_t stream)
{
    const float* x      = (const float*)d_in[0];
    const int*   attn   = (const int*)  d_in[1];
    const float* w_attn = (const float*)d_in[2];
    const float* b_attn = (const float*)d_in[3];
    const float* w_proj = (const float*)d_in[4];
    const float* b_proj = (const float*)d_in[5];
    float* out = (float*)d_out;

    // ---- workspace (~210.3 MiB) ----
    char* ws = (char*)d_ws;
    size_t off = 0;
    auto alloc = [&](size_t bytes) { void* p = ws + off; off = (off + bytes + 255) & ~(size_t)255; return p; };
    float* qkv   = (float*)alloc((size_t)16384 * 3072 * 4);   // 192 MiB
    short* waThi = (short*)alloc((size_t)3072 * 1024 * 2);    // 6 MiB (tiled)
    short* waTlo = (short*)alloc((size_t)3072 * 1024 * 2);    // 6 MiB
    short* wpThi = (short*)alloc((size_t)1024 * 1024 * 2);    // 2 MiB
    short* wpTlo = (short*)alloc((size_t)1024 * 1024 * 2);    // 2 MiB
    short* kvbT  = (short*)alloc((size_t)128 * 8192 * 2);     // 2 MiB (kv^T tiled)
    float* ksum  = (float*)alloc((size_t)128 * 64 * 4);       // 32 KiB

    // ---- d_out doubles as scratch before GEMM2 rewrites it ----
    short* xhi = (short*)d_out;                               // 32 MiB (tiled)
    short* xlo = xhi + (size_t)16384 * 1024;                  // 32 MiB
    float* kvpart = (float*)d_out;                            // 16 MiB (after GEMM1)
    float* kspart = (float*)((char*)d_out + (size_t)128 * 8 * 4096 * 4); // 256 KiB

    // 1) split x -> tiled bf16 hi/lo (into d_out)
    split_tile_kernel<<<dim3(1024, 8), 256, 0, stream>>>(x, xhi, xlo);
    // 2) transpose+split weights into tiled layout (into ws)
    w_tile_kernel<<<1536, 256, 0, stream>>>(w_attn, 3072, waThi, waTlo);  // 6144 tiles
    w_tile_kernel<<<512, 256, 0, stream>>>(w_proj, 1024, wpThi, wpTlo);   // 2048 tiles
    // 3) qkv = x @ w_attn + b_attn  (M=16384,N=3072,K=1024), A+B tiled
    gemm3_kernel<0><<<dim3(12, 64), 512, 0, stream>>>(xhi, xlo, 0, waThi, waTlo, b_attn, qkv, 1024, 3072);
    // 4) kv partials (into d_out) + reduce -> kv^T tiled bf16 + ksum (into ws)
    kv_part_kernel<<<dim3(8, 128), 256, 0, stream>>>(qkv, attn, kvpart, kspart);
    kv_reduce_kernel<<<128, 256, 0, stream>>>(kvpart, kspart, kvbT, ksum);
    // 5) y (MFMA) -> split bf16, TILED into qkv's dead k-region
    attn_y_kernel<<<dim3(32, 128), 256, 0, stream>>>(qkv, kvbT, ksum);
    // 6) out = y @ w_proj + b_proj  (M=16384,N=1024,K=1024); A y-scratch tiled, B tiled
    gemm3_kernel<2><<<dim3(4, 64), 512, 0, stream>>>((const short*)qkv, (const short*)qkv, 0,
                                                     wpThi, wpTlo, b_proj, out, 1024, 1024);
}

// Round 7
// 553.795 us; speedup vs baseline: 1.0352x; 1.0352x over previous
//
#include <hip/hip_runtime.h>

// (B,T,C,H) = (8,2048,1024,16), D=64
#define Tdim 2048

typedef __attribute__((ext_vector_type(8))) short bf16x8;
typedef __attribute__((ext_vector_type(4))) float f32x4;
typedef __attribute__((ext_vector_type(4))) short short4v;

#define GLOBAL_U32(p) ((const __attribute__((address_space(1))) unsigned int*)(p))
#define LDS_U32(p)    ((__attribute__((address_space(3))) unsigned int*)(p))

// barrier with compiler memory fences (no instruction-order pinning)
#define BARRIER() do { asm volatile("" ::: "memory"); \
                       __builtin_amdgcn_s_barrier(); \
                       asm volatile("" ::: "memory"); } while (0)

__device__ __forceinline__ float phi_f(float x) {
    return x > 0.f ? (x + 1.f) : __expf(x);
}
// round-to-nearest-even fp32 -> bf16 (finite inputs only)
__device__ __forceinline__ short f2bf(float f) {
    unsigned u = __float_as_uint(f);
    u += 0x7fffu + ((u >> 16) & 1u);
    return (short)(u >> 16);
}
__device__ __forceinline__ float bf2f(short h) {
    return __uint_as_float(((unsigned)(unsigned short)h) << 16);
}

// ===========================================================================
// TILED layout: matrix [R x K] bf16 stored as tiles of 16 rows x 32 k.
// Tile (rt, kt) at ((rt*(K/32))+kt)*512 shorts; slot L (0..63) holds
// row rt*16+(L&15), k = kt*32+(L>>4)*8 .. +8.  One wave staging instr = 1 KB
// contiguous; fragment read = tile_base + lane*16B (conflict-free identity).
//
// Y-SCRATCH layout (GEMM2's A): same tile format, but tiles embedded in the
// dead k-region of qkv.  Tile (RT, kt, plane) at physical row RT*16 + hh
// (hh = kt>>1), shorts offset 2048 + ((kt&1)*2 + plane)*512.  Each tile is
// 1 KB contiguous => staging identical to TILED (wave-uniform + lane*16B).
//
// KVT layout (attn_y's B): per bh, kv^T[f=64][d=64] as TILED bf16:
// 8 hi tiles (tt = nt*2 + kt) at [0..4096) shorts, 8 lo tiles at [4096..8192).
// ===========================================================================

// ---------------------------------------------------------------------------
// Fused preprocessing (1 launch): blocks [0,8192) split x into tiled hi/lo;
// [8192,9728) tile w_attn^T; [9728,10240) tile w_proj^T.
// ---------------------------------------------------------------------------
__device__ __forceinline__ void w_tile_body(
    const float* __restrict__ W, int N,
    short* __restrict__ Thi, short* __restrict__ Tlo, int bid)
{
    const int tile = bid * 4 + (threadIdx.x >> 6);
    const int nt = tile >> 5;           // n-tile
    const int kt = tile & 31;           // k-tile
    const int lane = threadIdx.x & 63;
    const int n = nt * 16 + (lane & 15);
    const int k = kt * 32 + (lane >> 4) * 8;
    const float* wp = W + (size_t)k * N + n;
    bf16x8 h, l;
#pragma unroll
    for (int j = 0; j < 8; ++j) {
        const float v = wp[(size_t)j * N];
        const short hh = f2bf(v);
        h[j] = hh;
        l[j] = f2bf(v - bf2f(hh));
    }
    const size_t off = (size_t)tile * 512 + lane * 8;
    *(bf16x8*)(Thi + off) = h;
    *(bf16x8*)(Tlo + off) = l;
}

__global__ __launch_bounds__(256) void prep_kernel(
    const float* __restrict__ X, short* __restrict__ Hi, short* __restrict__ Lo,
    const float* __restrict__ Wa, short* __restrict__ WaHi, short* __restrict__ WaLo,
    const float* __restrict__ Wp, short* __restrict__ WpHi, short* __restrict__ WpLo)
{
    const int bid = blockIdx.x;
    if (bid < 8192) {
        // split x: 16 rows x 128 cols per block
        const int rt = bid >> 3;            // row-tile 0..1023
        const int cb = bid & 7;             // col-block 0..7
        const int t = threadIdx.x;
        const int rl = t >> 4;
        const int cc = t & 15;
        const float* xp = X + ((size_t)rt * 16 + rl) * 1024 + cb * 128 + cc * 8;
        const float4 a = *(const float4*)xp;
        const float4 b = *(const float4*)(xp + 4);
        float v[8] = {a.x, a.y, a.z, a.w, b.x, b.y, b.z, b.w};
        bf16x8 h, l;
#pragma unroll
        for (int j = 0; j < 8; ++j) {
            const short hh = f2bf(v[j]);
            h[j] = hh;
            l[j] = f2bf(v[j] - bf2f(hh));
        }
        const int kt = cb * 4 + (cc >> 2);
        const int slot = ((cc & 3) << 4) | rl;
        const size_t off = ((size_t)rt * 32 + kt) * 512 + slot * 8;
        *(bf16x8*)(Hi + off) = h;
        *(bf16x8*)(Lo + off) = l;
    } else if (bid < 8192 + 1536) {
        w_tile_body(Wa, 3072, WaHi, WaLo, bid - 8192);
    } else {
        w_tile_body(Wp, 1024, WpHi, WpLo, bid - 9728);
    }
}

// ---------------------------------------------------------------------------
// bf16x3 split-precision GEMM: C = (Ahi+Alo)[M,K] * (Bhi+Blo)^T[N,K] + bias
// (drops lo*lo).
//
// 256x256 block tile, BK=32, 8 waves (2m x 4n), per-wave output 128x64.
// Double-buffered LDS (2 x 64 KiB).  COUNTED-VMCNT role-split schedule
// (round-5 proven: 247 us, MfmaUtil ~58%): waves 0-3 stage A-planes,
// waves 4-7 stage B-planes.  Per K-step:
//   P0: B-waves issue next-step loads | all read B(cur) frags |
//       A-waves s_waitcnt vmcnt(0) (loads one compute cluster old -> free)
//       | barrier
//   P1: A-waves issue next-step loads | A-reads + 96 MFMA (setprio) |
//       B-waves vmcnt(0) (covered by the MFMA cluster -> free) | barrier
//
// B always TILED.  AMODE 0: A TILED.  AMODE 2: A = y-scratch tiles embedded
// in qkv (see header comment).  Fragment read = identity lane*8.  K = 1024.
// ---------------------------------------------------------------------------
template<int AMODE>
__global__ __launch_bounds__(512, 2) void gemm3_kernel(
    const short* __restrict__ Ahi, const short* __restrict__ Alo, int lda,
    const short* __restrict__ BThi, const short* __restrict__ BTlo,
    const float* __restrict__ bias, float* __restrict__ C,
    int K, int ldc)
{
    // [2 buf][4 arrays][16 tiles][512 shorts] = 128 KiB
    __shared__ short smem[65536];
    const int tid = threadIdx.x;
    const int lane = tid & 63;
    const int wid = tid >> 6;            // wave 0..7
    const int bx = blockIdx.x, by = blockIdx.y;
    const int wm = wid >> 2, wn = wid & 3;

    const size_t tilestep = (size_t)(K >> 5) * 512;   // shorts per row-tile

    // staging: wave w stages 8 tiles of array sel (0:Ahi 1:Alo 2:Bhi 3:Blo),
    // half h (tiles h*8 .. h*8+7).  A-waves = wid 0..3, B-waves = wid 4..7.
    const int sel = wid >> 1, half = wid & 1;
    const bool is_a_wave = (wid < 4);
    const short* gptr;
    if (sel >= 2) {
        const short* gb = (sel == 2) ? BThi : BTlo;
        gptr = gb + (size_t)(bx * 16 + half * 8) * tilestep + lane * 8;
    } else if (AMODE == 0) {
        const short* gb = (sel == 0) ? Ahi : Alo;
        gptr = gb + (size_t)(by * 16 + half * 8) * tilestep + lane * 8;
    } else {
        // AMODE 2: y-scratch tiles in qkv; row-tile RT starts at physical
        // row RT*16; plane offset handled in the k-offset below.
        gptr = Ahi + (size_t)((by * 16 + half * 8) * 16) * 6144 + 2048 + lane * 8;
    }
    // wave-uniform LDS dest base (buffer 0)
    short* lw = smem + sel * 8192 + half * 4096;

    f32x4 acc[8][4];
#pragma unroll
    for (int i = 0; i < 8; ++i)
#pragma unroll
        for (int j = 0; j < 4; ++j) acc[i][j] = (f32x4){0.f, 0.f, 0.f, 0.f};

    auto stage = [&](int buf, int k0) {
        short* lb = lw + buf * 32768;
        if (AMODE == 0 || sel >= 2) {
            const short* g = gptr + (size_t)(k0 >> 5) * 512;
#pragma unroll
            for (int c = 0; c < 8; ++c)
                __builtin_amdgcn_global_load_lds(
                    GLOBAL_U32(g + (size_t)c * tilestep),
                    LDS_U32(lb + c * 512), 16, 0, 0);
        } else {
            // tile (RT, kt=k0>>5, plane=sel): row r = kt>>1 (= head), slot
            // s = (kt&1)*2 + plane; addr = (RT*16 + r)*6144 + 2048 + s*512
            const size_t koff = (size_t)(k0 >> 6) * 6144
                              + (size_t)((((k0 >> 5) & 1) << 1) | sel) * 512;
            const short* g = gptr + koff;
#pragma unroll
            for (int c = 0; c < 8; ++c)
                __builtin_amdgcn_global_load_lds(
                    GLOBAL_U32(g + (size_t)(c * 16) * 6144),
                    LDS_U32(lb + c * 512), 16, 0, 0);
        }
    };

    // prologue: fill buffer 0 completely (full drain + barrier, once)
    stage(0, 0);
    __syncthreads();

    const int fo = lane * 8;
    int cur = 0;
    for (int k0 = 0; k0 < K; k0 += 32) {
        const short* bp = smem + cur * 32768;
        // clamped next-step index: last iter re-stages k0=0 into the
        // never-read buffer (keeps per-wave vmcnt counts uniform)
        const int k0n = (k0 + 32 < K) ? (k0 + 32) : 0;

        // ---- P0: B-wave issue | B-reads | A-wave publish | barrier ----
        if (!is_a_wave) stage(cur ^ 1, k0n);
        bf16x8 bh[4], bl[4];
#pragma unroll
        for (int j = 0; j < 4; ++j) {
            bh[j] = *(const bf16x8*)(bp + 16384 + (wn * 4 + j) * 512 + fo);
            bl[j] = *(const bf16x8*)(bp + 24576 + (wn * 4 + j) * 512 + fo);
        }
        if (is_a_wave) asm volatile("s_waitcnt vmcnt(0)" ::: "memory");
        BARRIER();   // A(cur) now published by all A-waves

        // ---- P1: A-wave issue | A-reads + MFMA | B-wave publish | barrier --
        if (is_a_wave) stage(cur ^ 1, k0n);
        __builtin_amdgcn_s_setprio(1);
#pragma unroll
        for (int i = 0; i < 8; ++i) {
            const bf16x8 ah = *(const bf16x8*)(bp + (wm * 8 + i) * 512 + fo);
            const bf16x8 al = *(const bf16x8*)(bp + 8192 + (wm * 8 + i) * 512 + fo);
#pragma unroll
            for (int j = 0; j < 4; ++j) {
                acc[i][j] = __builtin_amdgcn_mfma_f32_16x16x32_bf16(ah, bh[j], acc[i][j], 0, 0, 0);
                acc[i][j] = __builtin_amdgcn_mfma_f32_16x16x32_bf16(al, bh[j], acc[i][j], 0, 0, 0);
                acc[i][j] = __builtin_amdgcn_mfma_f32_16x16x32_bf16(ah, bl[j], acc[i][j], 0, 0, 0);
            }
        }
        __builtin_amdgcn_s_setprio(0);
        if (!is_a_wave) asm volatile("s_waitcnt vmcnt(0)" ::: "memory");
        BARRIER();   // B(next) published; buf cur fully consumed
        cur ^= 1;
    }

    // epilogue: C/D layout col=lane&15, row=(lane>>4)*4+reg
    const int fr = lane & 15, fq = lane >> 4;
#pragma unroll
    for (int i = 0; i < 8; ++i) {
        const size_t row0 = (size_t)by * 256 + wm * 128 + i * 16 + fq * 4;
#pragma unroll
        for (int j = 0; j < 4; ++j) {
            const int col = bx * 256 + wn * 64 + j * 16 + fr;
            const float bv = bias[col];
            float* cp = C + row0 * (size_t)ldc + col;
#pragma unroll
            for (int r = 0; r < 4; ++r)
                cp[(size_t)r * ldc] = acc[i][j][r] + bv;
        }
    }
}

// ---------------------------------------------------------------------------
// Partial kv/ksum per (T-chunk, bh): 8 x 128 = 1024 blocks.
// ---------------------------------------------------------------------------
__global__ __launch_bounds__(256) void kv_part_kernel(
    const float* __restrict__ qkv, const int* __restrict__ attn,
    float* __restrict__ kvpart, float* __restrict__ kspart)
{
    __shared__ float ks[32][64];
    __shared__ float vs[32][64];

    const int chunk = blockIdx.x;       // 0..7
    const int bh = blockIdx.y;          // 0..127
    const int b = bh >> 4;
    const int h = bh & 15;
    const int tid = threadIdx.x;
    const int tx = tid & 15;
    const int ty = tid >> 4;
    const int l_t = tid >> 4;
    const int l_d = (tid & 15) << 2;

    const float* kb = qkv + (size_t)b * Tdim * 3072 + 1024 + h * 64;
    const float* vb = qkv + (size_t)b * Tdim * 3072 + 2048 + h * 64;
    const int* am = attn + b * Tdim;

    float acc[4][4];
#pragma unroll
    for (int i = 0; i < 4; ++i)
#pragma unroll
        for (int j = 0; j < 4; ++j) acc[i][j] = 0.f;
    float ksl = 0.f;

    for (int t0 = chunk * 256; t0 < (chunk + 1) * 256; t0 += 32) {
        __syncthreads();
#pragma unroll
        for (int rr = 0; rr < 2; ++rr) {
            const int t = l_t + rr * 16;
            const int gt = t0 + t;
            const float m = (am[gt] > 0) ? 1.f : 0.f;
            const float4 k4 = *(const float4*)(kb + (size_t)gt * 3072 + l_d);
            const float4 v4 = *(const float4*)(vb + (size_t)gt * 3072 + l_d);
            float4 kp, vp;
            kp.x = phi_f(k4.x) * m; kp.y = phi_f(k4.y) * m;
            kp.z = phi_f(k4.z) * m; kp.w = phi_f(k4.w) * m;
            vp.x = v4.x * m; vp.y = v4.y * m; vp.z = v4.z * m; vp.w = v4.w * m;
            *(float4*)&ks[t][l_d] = kp;
            *(float4*)&vs[t][l_d] = vp;
        }
        __syncthreads();
#pragma unroll
        for (int t = 0; t < 32; ++t) {
            float kr[4], vr[4];
            *(float4*)kr = *(const float4*)&ks[t][ty * 4];
            *(float4*)vr = *(const float4*)&vs[t][tx * 4];
#pragma unroll
            for (int i = 0; i < 4; ++i)
#pragma unroll
                for (int j = 0; j < 4; ++j)
                    acc[i][j] = fmaf(kr[i], vr[j], acc[i][j]);
        }
        if (tid < 64) {
#pragma unroll
            for (int t = 0; t < 32; ++t) ksl += ks[t][tid];
        }
    }

    float* ko = kvpart + ((size_t)bh * 8 + chunk) * 4096;
#pragma unroll
    for (int i = 0; i < 4; ++i) {
        float4 o;
        o.x = acc[i][0]; o.y = acc[i][1]; o.z = acc[i][2]; o.w = acc[i][3];
        *(float4*)(ko + (ty * 4 + i) * 64 + tx * 4) = o;
    }
    if (tid < 64) kspart[((size_t)bh * 8 + chunk) * 64 + tid] = ksl;
}

// ---------------------------------------------------------------------------
// Reduce partials AND emit kv^T as TILED bf16 hi/lo fragments (KVT layout)
// + ksum fp32.  Thread tid holds kv[d0+{0,16,32,48}][f0..f0+3] after the
// reduce (d0=tid>>4, f0=(tid&15)*4); transpose via padded LDS.
// ---------------------------------------------------------------------------
__global__ __launch_bounds__(256) void kv_reduce_kernel(
    const float* __restrict__ kvpart, const float* __restrict__ kspart,
    short* __restrict__ kvT, float* __restrict__ ksum)
{
    __shared__ float kvs[64][68];   // 68: rows 16B-aligned, bank-spread
    const int bh = blockIdx.x;
    const int tid = threadIdx.x;
    const float4* p = (const float4*)(kvpart + (size_t)bh * 8 * 4096);
    float4 s0 = {0,0,0,0}, s1 = {0,0,0,0}, s2 = {0,0,0,0}, s3 = {0,0,0,0};
#pragma unroll
    for (int c = 0; c < 8; ++c) {
        const int base = c * 1024;
        float4 a = p[base + tid], b = p[base + 256 + tid],
               cc = p[base + 512 + tid], d = p[base + 768 + tid];
        s0.x += a.x; s0.y += a.y; s0.z += a.z; s0.w += a.w;
        s1.x += b.x; s1.y += b.y; s1.z += b.z; s1.w += b.w;
        s2.x += cc.x; s2.y += cc.y; s2.z += cc.z; s2.w += cc.w;
        s3.x += d.x; s3.y += d.y; s3.z += d.z; s3.w += d.w;
    }
    const int d0 = tid >> 4, f0 = (tid & 15) * 4;
    *(float4*)&kvs[d0 +  0][f0] = s0;
    *(float4*)&kvs[d0 + 16][f0] = s1;
    *(float4*)&kvs[d0 + 32][f0] = s2;
    *(float4*)&kvs[d0 + 48][f0] = s3;
    __syncthreads();

    // emit 8 hi tiles + 8 lo tiles of kv^T[f][d] (TILED: row=f, k=d)
    short* kvb = kvT + (size_t)bh * 8192;
#pragma unroll
    for (int pp = 0; pp < 2; ++pp) {
        const int sid = tid * 2 + pp;       // 0..511
        const int tt = sid >> 6;            // tile 0..7 (nt*2+kt)
        const int L = sid & 63;
        const int nt = tt >> 1, kt = tt & 1;
        const int f = nt * 16 + (L & 15);
        const int dd = kt * 32 + (L >> 4) * 8;
        bf16x8 h, l;
#pragma unroll
        for (int e = 0; e < 8; ++e) {
            const float v = kvs[dd + e][f];
            const short hh = f2bf(v);
            h[e] = hh;
            l[e] = f2bf(v - bf2f(hh));
        }
        *(bf16x8*)(kvb + tt * 512 + L * 8) = h;
        *(bf16x8*)(kvb + 4096 + tt * 512 + L * 8) = l;
    }
    if (tid < 64) {
        float ss = 0.f;
#pragma unroll
        for (int c = 0; c < 8; ++c) ss += kspart[((size_t)bh * 8 + c) * 64 + tid];
        ksum[bh * 64 + tid] = ss;
    }
}

// ---------------------------------------------------------------------------
// MFMA attn_y (SWAPPED operands): acc = mfma(kvT_tile, phi_q) so C row = f,
// col = t.  Lane then holds 4 CONSECUTIVE f for one t -> y-scratch write is
// short4v (8 B) stores, not 2 B scatter (round-6's hidden regression).
// Block = (64 q-rows, bh); 4 waves x 16 rows.  kv^T staged via
// global_load_lds; q global->reg, phi+split in reg (B-frags: row=t=lane&15,
// k=(lane>>4)*8 — same lane mapping as before); denominator per-lane dot
// with ksum + shfl_xor; 24 MFMA/wave.  Output to Y-SCRATCH layout (GEMM2).
// ---------------------------------------------------------------------------
__global__ __launch_bounds__(256) void attn_y_kernel(
    float* __restrict__ qkv, const short* __restrict__ kvT,
    const float* __restrict__ ksumin)
{
    __shared__ short kvs[8192];       // 16 KiB: 8 hi + 8 lo tiles
    __shared__ float den_s[4][16];

    const int bh = blockIdx.y;
    const int b = bh >> 4;
    const int hh = bh & 15;
    const int t0 = blockIdx.x * 64;
    const int tid = threadIdx.x;
    const int lane = tid & 63;
    const int wid = tid >> 6;

    // stage kv^T tiles: wave w -> tiles w*4 .. w*4+3 (1 KB each, identity)
    {
        const short* src = kvT + (size_t)bh * 8192 + (wid * 4) * 512 + lane * 8;
        short* dst = kvs + (wid * 4) * 512;
#pragma unroll
        for (int t = 0; t < 4; ++t)
            __builtin_amdgcn_global_load_lds(
                GLOBAL_U32(src + t * 512), LDS_U32(dst + t * 512), 16, 0, 0);
    }

    // load q (global->reg), phi, denominator partial, hi/lo split
    const int grow = b * Tdim + t0 + wid * 16 + (lane & 15);
    const int kc = (lane >> 4) * 8;
    const float* qp = qkv + (size_t)grow * 3072 + hh * 64 + kc;
    const float* kp = ksumin + bh * 64 + kc;
    bf16x8 qh[2], ql[2];
    float den = 0.f;
#pragma unroll
    for (int ks = 0; ks < 2; ++ks) {
        const float4 a = *(const float4*)(qp + ks * 32);
        const float4 c = *(const float4*)(qp + ks * 32 + 4);
        const float4 u = *(const float4*)(kp + ks * 32);
        const float4 w = *(const float4*)(kp + ks * 32 + 4);
        float qv[8] = {a.x, a.y, a.z, a.w, c.x, c.y, c.z, c.w};
        float sv[8] = {u.x, u.y, u.z, u.w, w.x, w.y, w.z, w.w};
#pragma unroll
        for (int e = 0; e < 8; ++e) {
            const float ph = phi_f(qv[e]);
            den = fmaf(ph, sv[e], den);
            const short hi = f2bf(ph);
            qh[ks][e] = hi;
            ql[ks][e] = f2bf(ph - bf2f(hi));
        }
    }
    den += __shfl_xor(den, 16);
    den += __shfl_xor(den, 32);
    if ((lane >> 4) == 0) den_s[wid][lane & 15] = den;
    __syncthreads();     // staging (vmcnt) drained + den_s visible

    // acc[j] = kvT-tile-j (A) x phi_q (B): C row = f-local, col = t-local
    f32x4 acc[4];
#pragma unroll
    for (int j = 0; j < 4; ++j) acc[j] = (f32x4){0.f, 0.f, 0.f, 0.f};
#pragma unroll
    for (int j = 0; j < 4; ++j) {
#pragma unroll
        for (int ks = 0; ks < 2; ++ks) {
            const short* tb = kvs + (j * 2 + ks) * 512 + lane * 8;
            const bf16x8 ahf = *(const bf16x8*)tb;          // kv hi
            const bf16x8 alf = *(const bf16x8*)(tb + 4096); // kv lo
            acc[j] = __builtin_amdgcn_mfma_f32_16x16x32_bf16(ahf, qh[ks], acc[j], 0, 0, 0);
            acc[j] = __builtin_amdgcn_mfma_f32_16x16x32_bf16(alf, qh[ks], acc[j], 0, 0, 0);
            acc[j] = __builtin_amdgcn_mfma_f32_16x16x32_bf16(ahf, ql[ks], acc[j], 0, 0, 0);
        }
    }

    // per-lane 1/den (col = t-local = lane&15)
    const float dinv = 1.f / fmaxf(den_s[wid][lane & 15], 1e-8f);

    // tiled y-scratch write: row t = t0+wid*16+(lane&15),
    // cols f = j*16 + fq*4 + r (4 consecutive -> short4v store)
    short* yb = (short*)qkv;
    const int RT = ((b * Tdim + t0) >> 4) + wid;
    const size_t rowbase = (size_t)(RT * 16 + hh) * 6144 + 2048;
    const int fq = lane >> 4;
    const int trow = lane & 15;
#pragma unroll
    for (int j = 0; j < 4; ++j) {
        short4v hv, lv;
#pragma unroll
        for (int r = 0; r < 4; ++r) {
            const float val = acc[j][r] * dinv;
            const short h = f2bf(val);
            hv[r] = h;
            lv[r] = f2bf(val - bf2f(h));
        }
        const int fbase = j * 16 + fq * 4;      // 4-aligned
        const int kl = fbase >> 5;              // k-tile within head (0/1)
        const int cc = (fbase & 31) >> 3;       // k-chunk within tile
        const int wi = fbase & 7;               // 0 or 4
        const size_t so = rowbase + (size_t)(kl * 2) * 512
                        + (size_t)((cc << 4) | trow) * 8 + wi;
        *(short4v*)(yb + so) = hv;              // hi plane
        *(short4v*)(yb + so + 512) = lv;        // lo plane
    }
}

// ---------------------------------------------------------------------------
extern "C" void kernel_launch(void* const* d_in, const int* in_sizes, int n_in,
                              void* d_out, int out_size, void* d_ws, size_t ws_size,
                              hipStream_t stream)
{
    const float* x      = (const float*)d_in[0];
    const int*   attn   = (const int*)  d_in[1];
    const float* w_attn = (const float*)d_in[2];
    const float* b_attn = (const float*)d_in[3];
    const float* w_proj = (const float*)d_in[4];
    const float* b_proj = (const float*)d_in[5];
    float* out = (float*)d_out;

    // ---- workspace (~210.3 MiB) ----
    char* ws = (char*)d_ws;
    size_t off = 0;
    auto alloc = [&](size_t bytes) { void* p = ws + off; off = (off + bytes + 255) & ~(size_t)255; return p; };
    float* qkv   = (float*)alloc((size_t)16384 * 3072 * 4);   // 192 MiB
    short* waThi = (short*)alloc((size_t)3072 * 1024 * 2);    // 6 MiB (tiled)
    short* waTlo = (short*)alloc((size_t)3072 * 1024 * 2);    // 6 MiB
    short* wpThi = (short*)alloc((size_t)1024 * 1024 * 2);    // 2 MiB
    short* wpTlo = (short*)alloc((size_t)1024 * 1024 * 2);    // 2 MiB
    short* kvbT  = (short*)alloc((size_t)128 * 8192 * 2);     // 2 MiB (kv^T tiled)
    float* ksum  = (float*)alloc((size_t)128 * 64 * 4);       // 32 KiB

    // ---- d_out doubles as scratch before GEMM2 rewrites it ----
    short* xhi = (short*)d_out;                               // 32 MiB (tiled)
    short* xlo = xhi + (size_t)16384 * 1024;                  // 32 MiB
    float* kvpart = (float*)d_out;                            // 16 MiB (after GEMM1)
    float* kspart = (float*)((char*)d_out + (size_t)128 * 8 * 4096 * 4); // 256 KiB

    // 1) fused prep: split x (into d_out) + tile both weights (into ws)
    prep_kernel<<<10240, 256, 0, stream>>>(x, xhi, xlo,
                                           w_attn, waThi, waTlo,
                                           w_proj, wpThi, wpTlo);
    // 2) qkv = x @ w_attn + b_attn  (M=16384,N=3072,K=1024), A+B tiled
    gemm3_kernel<0><<<dim3(12, 64), 512, 0, stream>>>(xhi, xlo, 0, waThi, waTlo, b_attn, qkv, 1024, 3072);
    // 3) kv partials (into d_out) + reduce -> kv^T tiled bf16 + ksum (into ws)
    kv_part_kernel<<<dim3(8, 128), 256, 0, stream>>>(qkv, attn, kvpart, kspart);
    kv_reduce_kernel<<<128, 256, 0, stream>>>(kvpart, kspart, kvbT, ksum);
    // 4) y (MFMA, swapped operands) -> split bf16, TILED into qkv's dead k-region
    attn_y_kernel<<<dim3(32, 128), 256, 0, stream>>>(qkv, kvbT, ksum);
    // 5) out = y @ w_proj + b_proj  (M=16384,N=1024,K=1024); A y-scratch tiled, B tiled
    gemm3_kernel<2><<<dim3(4, 64), 512, 0, stream>>>((const short*)qkv, (const short*)qkv, 0,
                                                     wpThi, wpTlo, b_proj, out, 1024, 1024);
}

// Round 8
// 513.628 us; speedup vs baseline: 1.1161x; 1.0782x over previous
//
#include <hip/hip_runtime.h>

// (B,T,C,H) = (8,2048,1024,16), D=64
#define Tdim 2048

typedef __attribute__((ext_vector_type(8))) short bf16x8;
typedef __attribute__((ext_vector_type(4))) float f32x4;
typedef __attribute__((ext_vector_type(4))) short short4v;

#define GLOBAL_U32(p) ((const __attribute__((address_space(1))) unsigned int*)(p))
#define LDS_U32(p)    ((__attribute__((address_space(3))) unsigned int*)(p))

// barrier with compiler memory fences (no instruction-order pinning)
#define BARRIER() do { asm volatile("" ::: "memory"); \
                       __builtin_amdgcn_s_barrier(); \
                       asm volatile("" ::: "memory"); } while (0)

__device__ __forceinline__ float phi_f(float x) {
    return x > 0.f ? (x + 1.f) : __expf(x);
}
// round-to-nearest-even fp32 -> bf16 (finite inputs only)
__device__ __forceinline__ short f2bf(float f) {
    unsigned u = __float_as_uint(f);
    u += 0x7fffu + ((u >> 16) & 1u);
    return (short)(u >> 16);
}
__device__ __forceinline__ float bf2f(short h) {
    return __uint_as_float(((unsigned)(unsigned short)h) << 16);
}

// ===========================================================================
// TILED layout: matrix [R x K] bf16 stored as tiles of 16 rows x 32 k.
// Tile (rt, kt) at ((rt*(K/32))+kt)*512 shorts; slot L (0..63) holds
// row rt*16+(L&15), k = kt*32+(L>>4)*8 .. +8.  One wave staging instr = 1 KB
// contiguous; fragment read = tile_base + lane*16B (conflict-free identity).
//
// KT/VT layout (kv_mfma operands, written by GEMM1 epilogue): per bh,
// phi_k^T / v^T as TILED with R=64 (feature d/f), K=2048 (t): tile (rf, kt)
// at (rf*64 + kt)*512 shorts; 131072 shorts per bh per plane (hi/lo arrays).
//
// Y layout (GEMM2's A, written by attn_y into the dead VT region):
// standard TILED R=16384, K=1024 -> tile (RT, ktc) at (RT*32+ktc)*512.
//
// KVT layout (attn_y's B): per bh, kv^T[f=64][d=64] as TILED bf16:
// 8 hi tiles (tt = nt*2 + kt) at [0..4096) shorts, 8 lo tiles at [4096..8192).
// ===========================================================================

// ---------------------------------------------------------------------------
// Fused preprocessing (1 launch): blocks [0,8192) split x into tiled hi/lo;
// [8192,9728) tile w_attn^T; [9728,10240) tile w_proj^T.
// ---------------------------------------------------------------------------
__device__ __forceinline__ void w_tile_body(
    const float* __restrict__ W, int N,
    short* __restrict__ Thi, short* __restrict__ Tlo, int bid)
{
    const int tile = bid * 4 + (threadIdx.x >> 6);
    const int nt = tile >> 5;           // n-tile
    const int kt = tile & 31;           // k-tile
    const int lane = threadIdx.x & 63;
    const int n = nt * 16 + (lane & 15);
    const int k = kt * 32 + (lane >> 4) * 8;
    const float* wp = W + (size_t)k * N + n;
    bf16x8 h, l;
#pragma unroll
    for (int j = 0; j < 8; ++j) {
        const float v = wp[(size_t)j * N];
        const short hh = f2bf(v);
        h[j] = hh;
        l[j] = f2bf(v - bf2f(hh));
    }
    const size_t off = (size_t)tile * 512 + lane * 8;
    *(bf16x8*)(Thi + off) = h;
    *(bf16x8*)(Tlo + off) = l;
}

__global__ __launch_bounds__(256) void prep_kernel(
    const float* __restrict__ X, short* __restrict__ Hi, short* __restrict__ Lo,
    const float* __restrict__ Wa, short* __restrict__ WaHi, short* __restrict__ WaLo,
    const float* __restrict__ Wp, short* __restrict__ WpHi, short* __restrict__ WpLo)
{
    const int bid = blockIdx.x;
    if (bid < 8192) {
        // split x: 16 rows x 128 cols per block
        const int rt = bid >> 3;            // row-tile 0..1023
        const int cb = bid & 7;             // col-block 0..7
        const int t = threadIdx.x;
        const int rl = t >> 4;
        const int cc = t & 15;
        const float* xp = X + ((size_t)rt * 16 + rl) * 1024 + cb * 128 + cc * 8;
        const float4 a = *(const float4*)xp;
        const float4 b = *(const float4*)(xp + 4);
        float v[8] = {a.x, a.y, a.z, a.w, b.x, b.y, b.z, b.w};
        bf16x8 h, l;
#pragma unroll
        for (int j = 0; j < 8; ++j) {
            const short hh = f2bf(v[j]);
            h[j] = hh;
            l[j] = f2bf(v[j] - bf2f(hh));
        }
        const int kt = cb * 4 + (cc >> 2);
        const int slot = ((cc & 3) << 4) | rl;
        const size_t off = ((size_t)rt * 32 + kt) * 512 + slot * 8;
        *(bf16x8*)(Hi + off) = h;
        *(bf16x8*)(Lo + off) = l;
    } else if (bid < 8192 + 1536) {
        w_tile_body(Wa, 3072, WaHi, WaLo, bid - 8192);
    } else {
        w_tile_body(Wp, 1024, WpHi, WpLo, bid - 9728);
    }
}

// ---------------------------------------------------------------------------
// bf16x3 split-precision GEMM: C = (Ahi+Alo)[M,K] * (Bhi+Blo)^T[N,K] + bias
// (drops lo*lo).  256x256 tile, BK=32, 8 waves, per-wave 128x64.
// Double-buffered LDS (2 x 64 KiB).  COUNTED-VMCNT role-split schedule
// (round-5 proven: 247 us, MfmaUtil ~57%).  A and B both TILED.
//
// MODE 0: plain C + bias write (ldc).
// MODE 1: qkv epilogue — N=3072 split by section (bx>>2): q -> fp32 Q
//   (ldc=1024); k -> phi(k+b)*mask as bf16 hi/lo TILED-over-t into KT;
//   v -> (v+b)*mask hi/lo into VT.  Section is block-uniform.
// ---------------------------------------------------------------------------
template<int MODE>
__global__ __launch_bounds__(512, 2) void gemm3_kernel(
    const short* __restrict__ Ahi, const short* __restrict__ Alo,
    const short* __restrict__ BThi, const short* __restrict__ BTlo,
    const float* __restrict__ bias, float* __restrict__ C,
    int K, int ldc,
    short* __restrict__ KThi, short* __restrict__ KTlo,
    short* __restrict__ VThi, short* __restrict__ VTlo,
    const int* __restrict__ attn)
{
    // [2 buf][4 arrays][16 tiles][512 shorts] = 128 KiB
    __shared__ short smem[65536];
    const int tid = threadIdx.x;
    const int lane = tid & 63;
    const int wid = tid >> 6;            // wave 0..7
    const int bx = blockIdx.x, by = blockIdx.y;
    const int wm = wid >> 2, wn = wid & 3;

    const size_t tilestep = (size_t)(K >> 5) * 512;   // shorts per row-tile

    // staging: wave w stages 8 tiles of array sel (0:Ahi 1:Alo 2:Bhi 3:Blo),
    // half h (tiles h*8 .. h*8+7).  A-waves = wid 0..3, B-waves = wid 4..7.
    const int sel = wid >> 1, half = wid & 1;
    const bool is_a_wave = (wid < 4);
    const short* gptr;
    if (sel >= 2) {
        const short* gb = (sel == 2) ? BThi : BTlo;
        gptr = gb + (size_t)(bx * 16 + half * 8) * tilestep + lane * 8;
    } else {
        const short* gb = (sel == 0) ? Ahi : Alo;
        gptr = gb + (size_t)(by * 16 + half * 8) * tilestep + lane * 8;
    }
    // wave-uniform LDS dest base (buffer 0)
    short* lw = smem + sel * 8192 + half * 4096;

    f32x4 acc[8][4];
#pragma unroll
    for (int i = 0; i < 8; ++i)
#pragma unroll
        for (int j = 0; j < 4; ++j) acc[i][j] = (f32x4){0.f, 0.f, 0.f, 0.f};

    auto stage = [&](int buf, int k0) {
        short* lb = lw + buf * 32768;
        const short* g = gptr + (size_t)(k0 >> 5) * 512;
#pragma unroll
        for (int c = 0; c < 8; ++c)
            __builtin_amdgcn_global_load_lds(
                GLOBAL_U32(g + (size_t)c * tilestep),
                LDS_U32(lb + c * 512), 16, 0, 0);
    };

    // prologue: fill buffer 0 completely (full drain + barrier, once)
    stage(0, 0);
    __syncthreads();

    const int fo = lane * 8;
    int cur = 0;
    for (int k0 = 0; k0 < K; k0 += 32) {
        const short* bp = smem + cur * 32768;
        // clamped next-step index: last iter re-stages k0=0 into the
        // never-read buffer (keeps per-wave vmcnt counts uniform)
        const int k0n = (k0 + 32 < K) ? (k0 + 32) : 0;

        // ---- P0: B-wave issue | B-reads | A-wave publish | barrier ----
        if (!is_a_wave) stage(cur ^ 1, k0n);
        bf16x8 bh[4], bl[4];
#pragma unroll
        for (int j = 0; j < 4; ++j) {
            bh[j] = *(const bf16x8*)(bp + 16384 + (wn * 4 + j) * 512 + fo);
            bl[j] = *(const bf16x8*)(bp + 24576 + (wn * 4 + j) * 512 + fo);
        }
        if (is_a_wave) asm volatile("s_waitcnt vmcnt(0)" ::: "memory");
        BARRIER();   // A(cur) now published by all A-waves

        // ---- P1: A-wave issue | A-reads + MFMA | B-wave publish | barrier --
        if (is_a_wave) stage(cur ^ 1, k0n);
        __builtin_amdgcn_s_setprio(1);
#pragma unroll
        for (int i = 0; i < 8; ++i) {
            const bf16x8 ah = *(const bf16x8*)(bp + (wm * 8 + i) * 512 + fo);
            const bf16x8 al = *(const bf16x8*)(bp + 8192 + (wm * 8 + i) * 512 + fo);
#pragma unroll
            for (int j = 0; j < 4; ++j) {
                acc[i][j] = __builtin_amdgcn_mfma_f32_16x16x32_bf16(ah, bh[j], acc[i][j], 0, 0, 0);
                acc[i][j] = __builtin_amdgcn_mfma_f32_16x16x32_bf16(al, bh[j], acc[i][j], 0, 0, 0);
                acc[i][j] = __builtin_amdgcn_mfma_f32_16x16x32_bf16(ah, bl[j], acc[i][j], 0, 0, 0);
            }
        }
        __builtin_amdgcn_s_setprio(0);
        if (!is_a_wave) asm volatile("s_waitcnt vmcnt(0)" ::: "memory");
        BARRIER();   // B(next) published; buf cur fully consumed
        cur ^= 1;
    }

    // epilogue: C/D layout col=lane&15, row=(lane>>4)*4+reg
    const int fr = lane & 15, fq = lane >> 4;
    const int sec = (MODE == 1) ? (bx >> 2) : 0;   // 0 q, 1 k, 2 v

    if (MODE == 0 || sec == 0) {
#pragma unroll
        for (int i = 0; i < 8; ++i) {
            const size_t row0 = (size_t)by * 256 + wm * 128 + i * 16 + fq * 4;
#pragma unroll
            for (int j = 0; j < 4; ++j) {
                const int col = bx * 256 + wn * 64 + j * 16 + fr;
                const float bv = bias[col];
                float* cp = C + row0 * (size_t)ldc + col;
#pragma unroll
                for (int r = 0; r < 4; ++r)
                    cp[(size_t)r * ldc] = acc[i][j][r] + bv;
            }
        }
    } else {
        // k / v section: transposed bf16 hi/lo TILED-over-t write
        const int b = by >> 3;                       // 256-row blocks, 8 per batch
        const int head = (bx - (sec == 1 ? 4 : 8)) * 4 + wn;
        const int bh = b * 16 + head;
        short* Phi = (sec == 1) ? KThi : VThi;
        short* Plo = (sec == 1) ? KTlo : VTlo;
        const size_t base = (size_t)bh * 131072;
        const int e0 = (fq & 1) * 4;
#pragma unroll
        for (int i = 0; i < 8; ++i) {
            const int row0 = by * 256 + wm * 128 + i * 16 + fq * 4;
            const int t = row0 & 2047;
            const int kt = t >> 5;
            const int Lrow = ((t >> 3) & 3) << 4;
            const int4 ap = *(const int4*)(attn + row0);
            const int mm[4] = {ap.x, ap.y, ap.z, ap.w};
#pragma unroll
            for (int j = 0; j < 4; ++j) {
                const int col = bx * 256 + wn * 64 + j * 16 + fr;
                const float bv = bias[col];
                short4v hv, lv;
#pragma unroll
                for (int r = 0; r < 4; ++r) {
                    float val = acc[i][j][r] + bv;
                    if (sec == 1) val = phi_f(val);
                    val = (mm[r] > 0) ? val : 0.f;
                    const short h = f2bf(val);
                    hv[r] = h;
                    lv[r] = f2bf(val - bf2f(h));
                }
                // d-local in head = j*16 + fr -> tile row-d = j, L-row = fr
                const size_t addr = base + (size_t)(j * 64 + kt) * 512
                                  + (size_t)(Lrow | fr) * 8 + e0;
                *(short4v*)(Phi + addr) = hv;
                *(short4v*)(Plo + addr) = lv;
            }
        }
    }
}

// ---------------------------------------------------------------------------
// kv^T partials via bf16x3 MFMA: kvT[f][d] = sum_t v[t][f] * phi_k[t][d].
// Grid (4 t-chunks, 128 bh); 4 waves; wave w owns f-tile w and stages the
// (rf=w) A-tiles + (rd=w) B-tiles.  ksum partial via ones-vector MFMA
// (wave w covers d in [w*16,(w+1)*16)).  Writes fp32 partials [f][d].
// ---------------------------------------------------------------------------
__global__ __launch_bounds__(256) void kv_mfma_kernel(
    const short* __restrict__ KThi, const short* __restrict__ KTlo,
    const short* __restrict__ VThi, const short* __restrict__ VTlo,
    float* __restrict__ kvpart, float* __restrict__ kspart)
{
    __shared__ short smem[2][16][512];   // 32 KiB staging
    __shared__ float kvs2[64][68];       // fp32 transpose staging
    const int c = blockIdx.x;            // t-chunk 0..3 (512 t each)
    const int bh = blockIdx.y;
    const int tid = threadIdx.x;
    const int lane = tid & 63;
    const int w = tid >> 6;

    const size_t base = (size_t)bh * 131072 + (size_t)(w * 64) * 512 + lane * 8;
    const short* va = VThi + base;
    const short* vl = VTlo + base;
    const short* ka = KThi + base;
    const short* kl = KTlo + base;

    f32x4 acc[4];
#pragma unroll
    for (int rd = 0; rd < 4; ++rd) acc[rd] = (f32x4){0.f, 0.f, 0.f, 0.f};
    f32x4 ksa = (f32x4){0.f, 0.f, 0.f, 0.f};
    bf16x8 ones;
#pragma unroll
    for (int e = 0; e < 8; ++e) ones[e] = (short)0x3F80;

    auto stage = [&](int buf, int kt) {
        __builtin_amdgcn_global_load_lds(GLOBAL_U32(va + (size_t)kt * 512),
                                         LDS_U32(&smem[buf][w][0]), 16, 0, 0);
        __builtin_amdgcn_global_load_lds(GLOBAL_U32(vl + (size_t)kt * 512),
                                         LDS_U32(&smem[buf][4 + w][0]), 16, 0, 0);
        __builtin_amdgcn_global_load_lds(GLOBAL_U32(ka + (size_t)kt * 512),
                                         LDS_U32(&smem[buf][8 + w][0]), 16, 0, 0);
        __builtin_amdgcn_global_load_lds(GLOBAL_U32(kl + (size_t)kt * 512),
                                         LDS_U32(&smem[buf][12 + w][0]), 16, 0, 0);
    };

    stage(0, c * 16);
    __syncthreads();
    int cur = 0;
    for (int s = 0; s < 16; ++s) {
        if (s + 1 < 16) stage(cur ^ 1, c * 16 + s + 1);
        const short* bp = &smem[cur][0][0];
        const bf16x8 ah = *(const bf16x8*)(bp + w * 512 + lane * 8);
        const bf16x8 al = *(const bf16x8*)(bp + (4 + w) * 512 + lane * 8);
#pragma unroll
        for (int rd = 0; rd < 4; ++rd) {
            const bf16x8 bhf = *(const bf16x8*)(bp + (8 + rd) * 512 + lane * 8);
            const bf16x8 blf = *(const bf16x8*)(bp + (12 + rd) * 512 + lane * 8);
            acc[rd] = __builtin_amdgcn_mfma_f32_16x16x32_bf16(ah, bhf, acc[rd], 0, 0, 0);
            acc[rd] = __builtin_amdgcn_mfma_f32_16x16x32_bf16(al, bhf, acc[rd], 0, 0, 0);
            acc[rd] = __builtin_amdgcn_mfma_f32_16x16x32_bf16(ah, blf, acc[rd], 0, 0, 0);
            if (rd == w) {
                ksa = __builtin_amdgcn_mfma_f32_16x16x32_bf16(ones, bhf, ksa, 0, 0, 0);
                ksa = __builtin_amdgcn_mfma_f32_16x16x32_bf16(ones, blf, ksa, 0, 0, 0);
            }
        }
        __syncthreads();
        cur ^= 1;
    }

    // transpose to [f][d] via LDS, write fp32 partials vectorized
    const int fr = lane & 15, fq = lane >> 4;
#pragma unroll
    for (int rd = 0; rd < 4; ++rd)
#pragma unroll
        for (int r = 0; r < 4; ++r)
            kvs2[w * 16 + fq * 4 + r][rd * 16 + fr] = acc[rd][r];
    if (lane < 16)
        kspart[((size_t)c * 128 + bh) * 64 + w * 16 + lane] = ksa[0];
    __syncthreads();

    float* kp = kvpart + ((size_t)c * 128 + bh) * 4096;
#pragma unroll
    for (int i = 0; i < 4; ++i) {
        const int idx = i * 256 + tid;
        const int f = idx >> 4, d0 = (idx & 15) * 4;
        *(float4*)(kp + f * 64 + d0) = *(const float4*)&kvs2[f][d0];
    }
}

// ---------------------------------------------------------------------------
// Sum 4 chunk partials, emit KVT (tiled bf16 hi/lo kv^T) + ksum fp32.
// ---------------------------------------------------------------------------
__global__ __launch_bounds__(256) void kv_emit_kernel(
    const float* __restrict__ kvpart, const float* __restrict__ kspart,
    short* __restrict__ kvT, float* __restrict__ ksum)
{
    __shared__ float kvsE[64][68];
    const int bh = blockIdx.x;
    const int tid = threadIdx.x;
#pragma unroll
    for (int i = 0; i < 4; ++i) {
        const int idx = i * 256 + tid;
        const int f = idx >> 4, d0 = (idx & 15) * 4;
        float4 s = {0.f, 0.f, 0.f, 0.f};
#pragma unroll
        for (int c = 0; c < 4; ++c) {
            const float4 p = *(const float4*)(kvpart
                + ((size_t)c * 128 + bh) * 4096 + f * 64 + d0);
            s.x += p.x; s.y += p.y; s.z += p.z; s.w += p.w;
        }
        *(float4*)&kvsE[f][d0] = s;
    }
    __syncthreads();

    short* kvb = kvT + (size_t)bh * 8192;
#pragma unroll
    for (int pp = 0; pp < 2; ++pp) {
        const int sid = tid * 2 + pp;       // 0..511
        const int tt = sid >> 6;            // tile 0..7 (nt*2+kt)
        const int L = sid & 63;
        const int nt = tt >> 1, kt = tt & 1;
        const int f = nt * 16 + (L & 15);
        const int dd = kt * 32 + (L >> 4) * 8;
        bf16x8 h, l;
#pragma unroll
        for (int e = 0; e < 8; ++e) {
            const float v = kvsE[f][dd + e];
            const short hh = f2bf(v);
            h[e] = hh;
            l[e] = f2bf(v - bf2f(hh));
        }
        *(bf16x8*)(kvb + tt * 512 + L * 8) = h;
        *(bf16x8*)(kvb + 4096 + tt * 512 + L * 8) = l;
    }
    if (tid < 64) {
        float ss = 0.f;
#pragma unroll
        for (int c = 0; c < 4; ++c)
            ss += kspart[((size_t)c * 128 + bh) * 64 + tid];
        ksum[bh * 64 + tid] = ss;
    }
}

// ---------------------------------------------------------------------------
// MFMA attn_y (swapped operands, round-7 proven): acc = mfma(kvT, phi_q),
// C row = f, col = t -> short4v y writes.  Reads Q (row stride 1024);
// writes y hi/lo in STANDARD TILED layout (R=16384, K=1024) into Yhi/Ylo.
// ---------------------------------------------------------------------------
__global__ __launch_bounds__(256) void attn_y_kernel(
    const float* __restrict__ Q, const short* __restrict__ kvT,
    const float* __restrict__ ksumin,
    short* __restrict__ Yhi, short* __restrict__ Ylo)
{
    __shared__ short kvs[8192];       // 16 KiB: 8 hi + 8 lo tiles
    __shared__ float den_s[4][16];

    const int bh = blockIdx.y;
    const int b = bh >> 4;
    const int hh = bh & 15;
    const int t0 = blockIdx.x * 64;
    const int tid = threadIdx.x;
    const int lane = tid & 63;
    const int wid = tid >> 6;

    // stage kv^T tiles: wave w -> tiles w*4 .. w*4+3 (1 KB each, identity)
    {
        const short* src = kvT + (size_t)bh * 8192 + (wid * 4) * 512 + lane * 8;
        short* dst = kvs + (wid * 4) * 512;
#pragma unroll
        for (int t = 0; t < 4; ++t)
            __builtin_amdgcn_global_load_lds(
                GLOBAL_U32(src + t * 512), LDS_U32(dst + t * 512), 16, 0, 0);
    }

    // load q (global->reg), phi, denominator partial, hi/lo split
    const int grow = b * Tdim + t0 + wid * 16 + (lane & 15);
    const int kc = (lane >> 4) * 8;
    const float* qp = Q + (size_t)grow * 1024 + hh * 64 + kc;
    const float* kp = ksumin + bh * 64 + kc;
    bf16x8 qh[2], ql[2];
    float den = 0.f;
#pragma unroll
    for (int ks = 0; ks < 2; ++ks) {
        const float4 a = *(const float4*)(qp + ks * 32);
        const float4 c = *(const float4*)(qp + ks * 32 + 4);
        const float4 u = *(const float4*)(kp + ks * 32);
        const float4 w = *(const float4*)(kp + ks * 32 + 4);
        float qv[8] = {a.x, a.y, a.z, a.w, c.x, c.y, c.z, c.w};
        float sv[8] = {u.x, u.y, u.z, u.w, w.x, w.y, w.z, w.w};
#pragma unroll
        for (int e = 0; e < 8; ++e) {
            const float ph = phi_f(qv[e]);
            den = fmaf(ph, sv[e], den);
            const short hi = f2bf(ph);
            qh[ks][e] = hi;
            ql[ks][e] = f2bf(ph - bf2f(hi));
        }
    }
    den += __shfl_xor(den, 16);
    den += __shfl_xor(den, 32);
    if ((lane >> 4) == 0) den_s[wid][lane & 15] = den;
    __syncthreads();     // staging (vmcnt) drained + den_s visible

    // acc[j] = kvT-tile-j (A) x phi_q (B): C row = f-local, col = t-local
    f32x4 acc[4];
#pragma unroll
    for (int j = 0; j < 4; ++j) acc[j] = (f32x4){0.f, 0.f, 0.f, 0.f};
#pragma unroll
    for (int j = 0; j < 4; ++j) {
#pragma unroll
        for (int ks = 0; ks < 2; ++ks) {
            const short* tb = kvs + (j * 2 + ks) * 512 + lane * 8;
            const bf16x8 ahf = *(const bf16x8*)tb;          // kv hi
            const bf16x8 alf = *(const bf16x8*)(tb + 4096); // kv lo
            acc[j] = __builtin_amdgcn_mfma_f32_16x16x32_bf16(ahf, qh[ks], acc[j], 0, 0, 0);
            acc[j] = __builtin_amdgcn_mfma_f32_16x16x32_bf16(alf, qh[ks], acc[j], 0, 0, 0);
            acc[j] = __builtin_amdgcn_mfma_f32_16x16x32_bf16(ahf, ql[ks], acc[j], 0, 0, 0);
        }
    }

    // per-lane 1/den (col = t-local = lane&15)
    const float dinv = 1.f / fmaxf(den_s[wid][lane & 15], 1e-8f);

    // standard TILED y write: row tg, cols f = hh*64 + j*16 + fq*4 + r
    const int fq = lane >> 4;
    const int trow = lane & 15;
    const int tg = b * Tdim + t0 + wid * 16 + trow;
    const int RT = tg >> 4;
    const int e0 = (fq & 1) * 4;
#pragma unroll
    for (int j = 0; j < 4; ++j) {
        short4v hv, lv;
#pragma unroll
        for (int r = 0; r < 4; ++r) {
            const float val = acc[j][r] * dinv;
            const short h = f2bf(val);
            hv[r] = h;
            lv[r] = f2bf(val - bf2f(h));
        }
        const int col = hh * 64 + j * 16 + fq * 4;
        const int ktc = col >> 5;
        const int L = (((col >> 3) & 3) << 4) | trow;
        const size_t addr = (size_t)(RT * 32 + ktc) * 512 + (size_t)L * 8 + e0;
        *(short4v*)(Yhi + addr) = hv;
        *(short4v*)(Ylo + addr) = lv;
    }
}

// ---------------------------------------------------------------------------
extern "C" void kernel_launch(void* const* d_in, const int* in_sizes, int n_in,
                              void* d_out, int out_size, void* d_ws, size_t ws_size,
                              hipStream_t stream)
{
    const float* x      = (const float*)d_in[0];
    const int*   attn   = (const int*)  d_in[1];
    const float* w_attn = (const float*)d_in[2];
    const float* b_attn = (const float*)d_in[3];
    const float* w_proj = (const float*)d_in[4];
    const float* b_proj = (const float*)d_in[5];
    float* out = (float*)d_out;

    // ---- workspace (~210.1 MiB) ----
    char* ws = (char*)d_ws;
    size_t off = 0;
    auto alloc = [&](size_t bytes) { void* p = ws + off; off = (off + bytes + 255) & ~(size_t)255; return p; };
    float* Q     = (float*)alloc((size_t)16384 * 1024 * 4);   // 64 MiB
    short* KThi  = (short*)alloc((size_t)128 * 131072 * 2);   // 32 MiB
    short* KTlo  = (short*)alloc((size_t)128 * 131072 * 2);   // 32 MiB
    short* VThi  = (short*)alloc((size_t)128 * 131072 * 2);   // 32 MiB (later: y hi)
    short* VTlo  = (short*)alloc((size_t)128 * 131072 * 2);   // 32 MiB (later: y lo)
    short* waThi = (short*)alloc((size_t)3072 * 1024 * 2);    // 6 MiB (tiled)
    short* waTlo = (short*)alloc((size_t)3072 * 1024 * 2);    // 6 MiB
    short* wpThi = (short*)alloc((size_t)1024 * 1024 * 2);    // 2 MiB
    short* wpTlo = (short*)alloc((size_t)1024 * 1024 * 2);    // 2 MiB
    short* kvbT  = (short*)alloc((size_t)128 * 8192 * 2);     // 2 MiB (kv^T tiled)
    float* ksum  = (float*)alloc((size_t)128 * 64 * 4);       // 32 KiB

    // ---- d_out doubles as scratch ----
    short* xhi = (short*)d_out;                               // 32 MiB (tiled)
    short* xlo = xhi + (size_t)16384 * 1024;                  // 32 MiB
    float* kvpart = (float*)d_out;                            // 8 MiB (after GEMM1)
    float* kspart = (float*)((char*)d_out + (size_t)4 * 128 * 4096 * 4); // 128 KiB

    // 1) fused prep: split x (into d_out) + tile both weights (into ws)
    prep_kernel<<<10240, 256, 0, stream>>>(x, xhi, xlo,
                                           w_attn, waThi, waTlo,
                                           w_proj, wpThi, wpTlo);
    // 2) GEMM1 (MODE 1): q -> Q fp32; k -> phi+mask bf16 KT; v -> mask bf16 VT
    gemm3_kernel<1><<<dim3(12, 64), 512, 0, stream>>>(
        xhi, xlo, waThi, waTlo, b_attn, Q, 1024, 1024,
        KThi, KTlo, VThi, VTlo, attn);
    // 3) kv^T partials via MFMA (into d_out) + emit KVT/ksum (into ws)
    kv_mfma_kernel<<<dim3(4, 128), 256, 0, stream>>>(KThi, KTlo, VThi, VTlo,
                                                     kvpart, kspart);
    kv_emit_kernel<<<128, 256, 0, stream>>>(kvpart, kspart, kvbT, ksum);
    // 4) y (MFMA) -> standard TILED y hi/lo into the dead VT region
    attn_y_kernel<<<dim3(32, 128), 256, 0, stream>>>(Q, kvbT, ksum, VThi, VTlo);
    // 5) GEMM2 (MODE 0): out = y @ w_proj + b_proj
    gemm3_kernel<0><<<dim3(4, 64), 512, 0, stream>>>(
        VThi, VTlo, wpThi, wpTlo, b_proj, out, 1024, 1024,
        nullptr, nullptr, nullptr, nullptr, nullptr);
}